// Round 1
// baseline (1049.068 us; speedup 1.0000x reference)
//
#include <hip/hip_runtime.h>
#include <stdint.h>

// ---------------------------------------------------------------------------
// DkNN: nearest-neighbor search (argmin over 1024x100000 distance matrix)
// + neighbor-label bincount + conformal p-values.
// Round 0: correct fp32 tiled GEMM w/ fused argmin epilogue.
// ---------------------------------------------------------------------------

__global__ void init_keys(unsigned long long* __restrict__ gkey, int B) {
    int i = blockIdx.x * 256 + threadIdx.x;
    if (i < B) gkey[i] = ~0ULL;
}

// One block (256 threads) per query row: normalize, subtract center, emit xq + ||xq||^2
__global__ void prep_queries(const float* __restrict__ x, const float* __restrict__ center,
                             float* __restrict__ xq, float* __restrict__ q2, int B) {
    int row = blockIdx.x;
    int tid = threadIdx.x;  // 256 threads, d = 256
    if (row >= B) return;
    float v = x[(size_t)row * 256 + tid];
    float ss = v * v;
    #pragma unroll
    for (int s = 1; s < 64; s <<= 1) ss += __shfl_xor(ss, s);
    __shared__ float partial[4];
    __shared__ float partial2[4];
    if ((tid & 63) == 0) partial[tid >> 6] = ss;
    __syncthreads();
    float tot = partial[0] + partial[1] + partial[2] + partial[3];
    float inv = 1.0f / sqrtf(tot);
    float val = v * inv - center[tid];
    xq[(size_t)row * 256 + tid] = val;
    float ss2 = val * val;
    #pragma unroll
    for (int s = 1; s < 64; s <<= 1) ss2 += __shfl_xor(ss2, s);
    if ((tid & 63) == 0) partial2[tid >> 6] = ss2;
    __syncthreads();
    if (tid == 0) q2[row] = partial2[0] + partial2[1] + partial2[2] + partial2[3];
}

// One wave per train row: ||X_t||^2
__global__ void train_norms(const float* __restrict__ X, float* __restrict__ xn2, int nb_train) {
    int row = blockIdx.x * 4 + (threadIdx.x >> 6);
    int lane = threadIdx.x & 63;
    if (row >= nb_train) return;
    const float4* p = (const float4*)(X + (size_t)row * 256);
    float4 v = p[lane];
    float ss = v.x * v.x + v.y * v.y + v.z * v.z + v.w * v.w;
    #pragma unroll
    for (int s = 1; s < 64; s <<= 1) ss += __shfl_xor(ss, s);
    if (lane == 0) xn2[row] = ss;
}

// 64(M) x 64(N) tile, K=256 in chunks of 16, LDS transposed for b128 compute reads.
// Epilogue: score = q2[m] - 2*dot + xn2[t], packed-u64 argmin -> atomicMin.
__global__ __launch_bounds__(256) void gemm_argmin(
    const float* __restrict__ xq, const float* __restrict__ q2,
    const float* __restrict__ X, const float* __restrict__ xn2,
    unsigned long long* __restrict__ gkey, int nb_train, int B)
{
    __shared__ float As[16][68];   // As[k][m], stride 68: staging 2-way, compute 2-way (free)
    __shared__ float Bs[16][68];   // Bs[k][n]
    const int tid = threadIdx.x;
    const int tx = tid & 15;       // n direction
    const int ty = tid >> 4;       // m direction
    const int mbase = blockIdx.y * 64;
    const int nbase = blockIdx.x * 64;
    const int lrow = tid >> 2;            // 0..63 (row being staged)
    const int lcol = (tid & 3) << 2;      // 0,4,8,12 (k offset)
    const bool avalid = (mbase + lrow) < B;
    const bool bvalid = (nbase + lrow) < nb_train;
    const float* Ap = xq + (size_t)(mbase + lrow) * 256 + lcol;
    const float* Bp = X  + (size_t)(nbase + lrow) * 256 + lcol;

    float acc[4][4] = {};

    for (int k0 = 0; k0 < 256; k0 += 16) {
        float4 av = avalid ? *(const float4*)(Ap + k0) : make_float4(0.f, 0.f, 0.f, 0.f);
        float4 bv = bvalid ? *(const float4*)(Bp + k0) : make_float4(0.f, 0.f, 0.f, 0.f);
        __syncthreads();
        As[lcol + 0][lrow] = av.x;
        As[lcol + 1][lrow] = av.y;
        As[lcol + 2][lrow] = av.z;
        As[lcol + 3][lrow] = av.w;
        Bs[lcol + 0][lrow] = bv.x;
        Bs[lcol + 1][lrow] = bv.y;
        Bs[lcol + 2][lrow] = bv.z;
        Bs[lcol + 3][lrow] = bv.w;
        __syncthreads();
        #pragma unroll
        for (int k = 0; k < 16; ++k) {
            float4 a = *(const float4*)&As[k][ty << 2];
            float4 b = *(const float4*)&Bs[k][tx << 2];
            acc[0][0] += a.x * b.x; acc[0][1] += a.x * b.y; acc[0][2] += a.x * b.z; acc[0][3] += a.x * b.w;
            acc[1][0] += a.y * b.x; acc[1][1] += a.y * b.y; acc[1][2] += a.y * b.z; acc[1][3] += a.y * b.w;
            acc[2][0] += a.z * b.x; acc[2][1] += a.z * b.y; acc[2][2] += a.z * b.z; acc[2][3] += a.z * b.w;
            acc[3][0] += a.w * b.x; acc[3][1] += a.w * b.y; acc[3][2] += a.w * b.z; acc[3][3] += a.w * b.w;
        }
    }

    // Epilogue: per-query argmin over this block's 64 train columns.
    #pragma unroll
    for (int i = 0; i < 4; ++i) {
        int mi = mbase + (ty << 2) + i;
        bool mvalid = mi < B;
        float q2v = mvalid ? q2[mi] : 0.0f;
        unsigned long long best = ~0ULL;
        #pragma unroll
        for (int j = 0; j < 4; ++j) {
            int t = nbase + (tx << 2) + j;
            if (t < nb_train && mvalid) {
                float sc = q2v - 2.0f * acc[i][j] + xn2[t];
                if (!(sc > 0.0f)) sc = 0.0f;   // guard bit-ordering (scores are >0 in practice)
                unsigned long long key =
                    ((unsigned long long)__float_as_uint(sc) << 32) | (unsigned int)t;
                if (key < best) best = key;
            }
        }
        // reduce across the 16 tx-lanes (same wave: lanes differing in bits 0..3)
        #pragma unroll
        for (int s = 1; s < 16; s <<= 1) {
            unsigned long long o = __shfl_xor(best, s);
            if (o < best) best = o;
        }
        if (tx == 0 && mvalid) atomicMin(gkey + mi, best);
    }
}

// Per query: gather 75 neighbor labels, bincount, searchsorted p-values, creds.
__global__ void classify(const unsigned long long* __restrict__ gkey,
                         const int* __restrict__ labels,
                         const int* __restrict__ nbr,
                         const int* __restrict__ cali,
                         float* __restrict__ out,
                         int knm1, int nb_cali, int B)
{
    __shared__ int scali[1024];
    __shared__ int cnt[256][10];
    int tid = threadIdx.x;
    for (int i = tid; i < nb_cali && i < 1024; i += 256) scali[i] = cali[i];
    #pragma unroll
    for (int c = 0; c < 10; ++c) cnt[tid][c] = 0;
    __syncthreads();
    int q = blockIdx.x * 256 + tid;
    if (q < B) {
        int closest = (int)(gkey[q] & 0xFFFFFFFFULL);
        int K = knm1 + 1;
        for (int j = 0; j < K; ++j) {
            int idx = (j == 0) ? closest : nbr[(size_t)closest * knm1 + (j - 1)];
            int lbl = labels[idx];
            cnt[tid][lbl]++;
        }
        int bestc = 0, bestp = -1;
        #pragma unroll
        for (int c = 0; c < 10; ++c) {
            int v = K - cnt[tid][c];
            int lo = 0, hi = nb_cali;
            while (lo < hi) {                 // bisect_left
                int mid = (lo + hi) >> 1;
                if (scali[mid] < v) lo = mid + 1; else hi = mid;
            }
            int p = nb_cali - lo;
            if (p > bestp) { bestp = p; bestc = c; }   // strict > == first-occurrence argmax
        }
        float pv = (float)bestp / (float)nb_cali;
        #pragma unroll
        for (int c = 0; c < 10; ++c)
            out[(size_t)q * 10 + c] = (c == bestc) ? pv : 0.0f;
    }
}

extern "C" void kernel_launch(void* const* d_in, const int* in_sizes, int n_in,
                              void* d_out, int out_size, void* d_ws, size_t ws_size,
                              hipStream_t stream) {
    const float* x      = (const float*)d_in[0];
    const float* X      = (const float*)d_in[1];
    const float* center = (const float*)d_in[2];
    const int* labels   = (const int*)d_in[3];
    const int* nbr      = (const int*)d_in[4];
    const int* cali     = (const int*)d_in[5];
    float* out = (float*)d_out;

    const int d        = in_sizes[2];              // 256
    const int B        = in_sizes[0] / d;          // 1024
    const int nb_train = in_sizes[3];              // 100000
    const int knm1     = in_sizes[4] / nb_train;   // 74
    const int nb_cali  = in_sizes[5];              // 1000

    char* ws = (char*)d_ws;
    size_t off = 0;
    unsigned long long* gkey = (unsigned long long*)(ws + off); off += (size_t)B * 8;
    float* xq  = (float*)(ws + off); off += (size_t)B * d * 4;
    float* q2  = (float*)(ws + off); off += (size_t)B * 4;
    float* xn2 = (float*)(ws + off); off += (size_t)nb_train * 4;

    init_keys<<<(B + 255) / 256, 256, 0, stream>>>(gkey, B);
    prep_queries<<<B, 256, 0, stream>>>(x, center, xq, q2, B);
    train_norms<<<(nb_train + 3) / 4, 256, 0, stream>>>(X, xn2, nb_train);
    dim3 grid((nb_train + 63) / 64, (B + 63) / 64);
    gemm_argmin<<<grid, 256, 0, stream>>>(xq, q2, X, xn2, gkey, nb_train, B);
    classify<<<(B + 255) / 256, 256, 0, stream>>>(gkey, labels, nbr, cali, out,
                                                  knm1, nb_cali, B);
}

// Round 2
// 804.187 us; speedup vs baseline: 1.3045x; 1.3045x over previous
//
#include <hip/hip_runtime.h>
#include <stdint.h>

// ---------------------------------------------------------------------------
// DkNN round 2: split-precision bf16 MFMA distance GEMM.
// dot_f32(a,b) ~= Ah.Bh + Ah.Bl + Al.Bh  (hi/lo bf16 decomposition, fp32 acc)
// LDS-free: MFMA fragments loaded directly from global (16B/lane, k-contig).
// ---------------------------------------------------------------------------

typedef __attribute__((ext_vector_type(8))) short short8;   // 8 bf16 = 4 VGPR
typedef __attribute__((ext_vector_type(4))) float float4v;  // MFMA C/D

static __device__ __forceinline__ unsigned short bf16_rn(float f) {
    unsigned int u = __float_as_uint(f);
    unsigned int r = (u + 0x7FFFu + ((u >> 16) & 1u)) >> 16;
    return (unsigned short)r;
}

__global__ void init_keys(unsigned long long* __restrict__ gkey, int B) {
    int i = blockIdx.x * 256 + threadIdx.x;
    if (i < B) gkey[i] = ~0ULL;
}

// One block per (padded) query row: normalize, center, emit bf16 hi/lo + ||xq||^2.
__global__ void prep_queries(const float* __restrict__ x, const float* __restrict__ center,
                             unsigned short* __restrict__ Ah, unsigned short* __restrict__ Al,
                             float* __restrict__ q2, int B, int Mp) {
    int row = blockIdx.x;
    int tid = threadIdx.x;  // 256 threads, d = 256
    if (row >= Mp) return;
    if (row >= B) {  // zero pad rows so MFMA on them is harmless
        Ah[(size_t)row * 256 + tid] = 0;
        Al[(size_t)row * 256 + tid] = 0;
        if (tid == 0) q2[row] = 0.0f;
        return;
    }
    float v = x[(size_t)row * 256 + tid];
    float ss = v * v;
    #pragma unroll
    for (int s = 1; s < 64; s <<= 1) ss += __shfl_xor(ss, s);
    __shared__ float partial[4];
    __shared__ float partial2[4];
    if ((tid & 63) == 0) partial[tid >> 6] = ss;
    __syncthreads();
    float tot = partial[0] + partial[1] + partial[2] + partial[3];
    float inv = 1.0f / sqrtf(tot);
    float val = v * inv - center[tid];
    unsigned short hb = bf16_rn(val);
    float hf = __uint_as_float((unsigned int)hb << 16);
    unsigned short lb = bf16_rn(val - hf);
    Ah[(size_t)row * 256 + tid] = hb;
    Al[(size_t)row * 256 + tid] = lb;
    float ss2 = val * val;
    #pragma unroll
    for (int s = 1; s < 64; s <<= 1) ss2 += __shfl_xor(ss2, s);
    if ((tid & 63) == 0) partial2[tid >> 6] = ss2;
    __syncthreads();
    if (tid == 0) q2[row] = partial2[0] + partial2[1] + partial2[2] + partial2[3];
}

// One wave per train row: bf16 hi/lo split + ||X_t||^2 (fp32). Pads zeroed, xn2=huge.
__global__ void conv_train(const float* __restrict__ X,
                           unsigned short* __restrict__ Bh, unsigned short* __restrict__ Bl,
                           float* __restrict__ xn2, int nb_train, int Np) {
    int row = blockIdx.x * 4 + (threadIdx.x >> 6);
    int lane = threadIdx.x & 63;
    if (row >= Np) return;
    if (row >= nb_train) {
        ushort4 z = make_ushort4(0, 0, 0, 0);
        *(ushort4*)(Bh + (size_t)row * 256 + lane * 4) = z;
        *(ushort4*)(Bl + (size_t)row * 256 + lane * 4) = z;
        if (lane == 0) xn2[row] = 3.0e38f;
        return;
    }
    float4 v = ((const float4*)(X + (size_t)row * 256))[lane];
    ushort4 h, l;
    h.x = bf16_rn(v.x); l.x = bf16_rn(v.x - __uint_as_float((unsigned)h.x << 16));
    h.y = bf16_rn(v.y); l.y = bf16_rn(v.y - __uint_as_float((unsigned)h.y << 16));
    h.z = bf16_rn(v.z); l.z = bf16_rn(v.z - __uint_as_float((unsigned)h.z << 16));
    h.w = bf16_rn(v.w); l.w = bf16_rn(v.w - __uint_as_float((unsigned)h.w << 16));
    *(ushort4*)(Bh + (size_t)row * 256 + lane * 4) = h;
    *(ushort4*)(Bl + (size_t)row * 256 + lane * 4) = l;
    float ss = v.x * v.x + v.y * v.y + v.z * v.z + v.w * v.w;
    #pragma unroll
    for (int s = 1; s < 64; s <<= 1) ss += __shfl_xor(ss, s);
    if (lane == 0) xn2[row] = ss;
}

// Block = 4 waves; wave w owns a 64(M) x 64(N) register tile at nbase+w*64.
// 3 products x 8 k-chunks x 16 MFMA(16x16x32). No LDS staging, no k-loop barriers.
// Epilogue: packed (score,idx) argmin -> LDS pre-reduce -> global atomicMin.
__global__ __launch_bounds__(256) void mfma_argmin(
    const unsigned short* __restrict__ Adata,  // [Ah | Al], each Mp*256
    const unsigned short* __restrict__ Bdata,  // [Bh | Bl], each Np*256
    const float* __restrict__ q2, const float* __restrict__ xn2,
    unsigned long long* __restrict__ gkey,
    int Mp, int Np, int nb_train, int B)
{
    const int tid  = threadIdx.x;
    const int wave = tid >> 6;
    const int lane = tid & 63;
    const int lrow = lane & 15;   // m (A) / n (B) within a 16-frag
    const int kseg = lane >> 4;   // k quarter: holds k = kseg*8 .. kseg*8+7
    const int mbase = blockIdx.y * 64;
    const int nbase = blockIdx.x * 256 + wave * 64;

    const size_t APROD = (size_t)Mp * 256;  // element stride Ah -> Al
    const size_t BPROD = (size_t)Np * 256;

    const unsigned short* Ap[4];
    const unsigned short* Bp[4];
    #pragma unroll
    for (int i = 0; i < 4; ++i)
        Ap[i] = Adata + (size_t)(mbase + i * 16 + lrow) * 256 + kseg * 8;
    #pragma unroll
    for (int j = 0; j < 4; ++j)
        Bp[j] = Bdata + (size_t)(nbase + j * 16 + lrow) * 256 + kseg * 8;

    float4v acc[4][4];
    #pragma unroll
    for (int i = 0; i < 4; ++i)
        #pragma unroll
        for (int j = 0; j < 4; ++j)
            acc[i][j] = (float4v){0.f, 0.f, 0.f, 0.f};

    #pragma unroll
    for (int prod = 0; prod < 3; ++prod) {
        const size_t ao = (prod == 2) ? APROD : 0;  // Al only in product 2
        const size_t bo = (prod == 1) ? BPROD : 0;  // Bl only in product 1
        #pragma unroll
        for (int kc = 0; kc < 8; ++kc) {
            const int ko = kc * 32;
            short8 a[4], b[4];
            #pragma unroll
            for (int i = 0; i < 4; ++i) a[i] = *(const short8*)(Ap[i] + ao + ko);
            #pragma unroll
            for (int j = 0; j < 4; ++j) b[j] = *(const short8*)(Bp[j] + bo + ko);
            #pragma unroll
            for (int i = 0; i < 4; ++i)
                #pragma unroll
                for (int j = 0; j < 4; ++j)
                    acc[i][j] = __builtin_amdgcn_mfma_f32_16x16x32_bf16(
                        a[i], b[j], acc[i][j], 0, 0, 0);
        }
    }

    // ---- epilogue: score = q2[m] - 2*dot + xn2[t]; argmin with index tiebreak ----
    __shared__ unsigned long long skey[64];
    if (tid < 64) skey[tid] = ~0ULL;
    __syncthreads();

    float xnv[4];
    #pragma unroll
    for (int j = 0; j < 4; ++j) {
        int t = nbase + j * 16 + lrow;
        xnv[j] = (t < nb_train) ? xn2[t] : 3.0e38f;
    }

    #pragma unroll
    for (int i = 0; i < 4; ++i) {
        #pragma unroll
        for (int r = 0; r < 4; ++r) {
            int lm = i * 16 + kseg * 4 + r;       // local query idx within 64
            int mi = mbase + lm;
            unsigned long long best = ~0ULL;
            if (mi < B) {
                float q2v = q2[mi];
                #pragma unroll
                for (int j = 0; j < 4; ++j) {
                    int t = nbase + j * 16 + lrow;
                    float sc = q2v - 2.0f * acc[i][j][r] + xnv[j];
                    sc = fmaxf(sc, 0.0f);  // keep float-bit ordering monotone
                    unsigned long long key =
                        ((unsigned long long)__float_as_uint(sc) << 32) | (unsigned int)t;
                    best = (key < best) ? key : best;
                }
            }
            // min across the 16 lanes of this k-quarter (bits 0..3 of lane)
            #pragma unroll
            for (int s = 1; s < 16; s <<= 1) {
                unsigned long long o = __shfl_xor(best, s);
                best = (o < best) ? o : best;
            }
            if (lrow == 0 && mi < B) atomicMin(&skey[lm], best);
        }
    }
    __syncthreads();
    if (tid < 64) {
        int mi = mbase + tid;
        if (mi < B && skey[tid] != ~0ULL) atomicMin(gkey + mi, skey[tid]);
    }
}

// Per query: gather 75 neighbor labels, bincount, searchsorted p-values, creds.
__global__ void classify(const unsigned long long* __restrict__ gkey,
                         const int* __restrict__ labels,
                         const int* __restrict__ nbr,
                         const int* __restrict__ cali,
                         float* __restrict__ out,
                         int knm1, int nb_cali, int B)
{
    __shared__ int scali[1024];
    __shared__ int cnt[256][10];
    int tid = threadIdx.x;
    for (int i = tid; i < nb_cali && i < 1024; i += 256) scali[i] = cali[i];
    #pragma unroll
    for (int c = 0; c < 10; ++c) cnt[tid][c] = 0;
    __syncthreads();
    int q = blockIdx.x * 256 + tid;
    if (q < B) {
        int closest = (int)(gkey[q] & 0xFFFFFFFFULL);
        int K = knm1 + 1;
        for (int j = 0; j < K; ++j) {
            int idx = (j == 0) ? closest : nbr[(size_t)closest * knm1 + (j - 1)];
            int lbl = labels[idx];
            cnt[tid][lbl]++;
        }
        int bestc = 0, bestp = -1;
        #pragma unroll
        for (int c = 0; c < 10; ++c) {
            int v = K - cnt[tid][c];
            int lo = 0, hi = nb_cali;
            while (lo < hi) {                 // bisect_left
                int mid = (lo + hi) >> 1;
                if (scali[mid] < v) lo = mid + 1; else hi = mid;
            }
            int p = nb_cali - lo;
            if (p > bestp) { bestp = p; bestc = c; }   // strict > == first-occurrence argmax
        }
        float pv = (float)bestp / (float)nb_cali;
        #pragma unroll
        for (int c = 0; c < 10; ++c)
            out[(size_t)q * 10 + c] = (c == bestc) ? pv : 0.0f;
    }
}

extern "C" void kernel_launch(void* const* d_in, const int* in_sizes, int n_in,
                              void* d_out, int out_size, void* d_ws, size_t ws_size,
                              hipStream_t stream) {
    const float* x      = (const float*)d_in[0];
    const float* X      = (const float*)d_in[1];
    const float* center = (const float*)d_in[2];
    const int* labels   = (const int*)d_in[3];
    const int* nbr      = (const int*)d_in[4];
    const int* cali     = (const int*)d_in[5];
    float* out = (float*)d_out;

    const int d        = in_sizes[2];              // 256
    const int B        = in_sizes[0] / d;          // 1024
    const int nb_train = in_sizes[3];              // 100000
    const int knm1     = in_sizes[4] / nb_train;   // 74
    const int nb_cali  = in_sizes[5];              // 1000

    const int Mp = (B + 63) & ~63;                 // 1024
    const int Np = (nb_train + 255) & ~255;        // 100096

    char* ws = (char*)d_ws;
    size_t off = 0;
    unsigned long long* gkey = (unsigned long long*)(ws + off); off += (size_t)Mp * 8;
    unsigned short* Adata = (unsigned short*)(ws + off); off += (size_t)Mp * 256 * 2 * 2;
    float* q2 = (float*)(ws + off); off += (size_t)Mp * 4;
    unsigned short* Bdata = (unsigned short*)(ws + off); off += (size_t)Np * 256 * 2 * 2;
    float* xn2 = (float*)(ws + off); off += (size_t)Np * 4;

    unsigned short* Ah = Adata;
    unsigned short* Al = Adata + (size_t)Mp * 256;
    unsigned short* Bh = Bdata;
    unsigned short* Bl = Bdata + (size_t)Np * 256;

    init_keys<<<(Mp + 255) / 256, 256, 0, stream>>>(gkey, Mp);
    prep_queries<<<Mp, 256, 0, stream>>>(x, center, Ah, Al, q2, B, Mp);
    conv_train<<<Np / 4, 256, 0, stream>>>(X, Bh, Bl, xn2, nb_train, Np);
    dim3 grid(Np / 256, Mp / 64);
    mfma_argmin<<<grid, 256, 0, stream>>>(Adata, Bdata, q2, xn2, gkey,
                                          Mp, Np, nb_train, B);
    classify<<<(B + 255) / 256, 256, 0, stream>>>(gkey, labels, nbr, cali, out,
                                                  knm1, nb_cali, B);
}

// Round 3
// 396.192 us; speedup vs baseline: 2.6479x; 2.0298x over previous
//
#include <hip/hip_runtime.h>
#include <stdint.h>

// ---------------------------------------------------------------------------
// DkNN round 3: m97-style LDS-staged bf16 MFMA GEMM, effective K=768
// (3-term hi/lo split as phased source selection), global_load_lds width=16,
// XOR-swizzled LDS layout (swizzle applied on the *source* address since the
// DMA writes lane-contiguous). Wave-parallel classify.
// ---------------------------------------------------------------------------

typedef __attribute__((ext_vector_type(8))) short short8;   // 8 bf16 = 4 VGPR
typedef __attribute__((ext_vector_type(4))) float float4v;  // MFMA C/D

static __device__ __forceinline__ unsigned short bf16_rn(float f) {
    unsigned int u = __float_as_uint(f);
    unsigned int r = (u + 0x7FFFu + ((u >> 16) & 1u)) >> 16;
    return (unsigned short)r;
}

static __device__ __forceinline__ void gload_lds16(const void* g, void* l) {
    __builtin_amdgcn_global_load_lds(
        (const __attribute__((address_space(1))) unsigned int*)g,
        (__attribute__((address_space(3))) unsigned int*)l, 16, 0, 0);
}

// One block per (padded) query row: normalize, center, bf16 hi/lo, ||xq||^2, gkey init.
__global__ void prep_queries(const float* __restrict__ x, const float* __restrict__ center,
                             unsigned short* __restrict__ Ah, unsigned short* __restrict__ Al,
                             float* __restrict__ q2, unsigned long long* __restrict__ gkey,
                             int B, int Mp) {
    int row = blockIdx.x;
    int tid = threadIdx.x;  // 256 threads, d = 256
    if (row >= Mp) return;
    if (tid == 0) gkey[row] = ~0ULL;
    if (row >= B) {  // zero pad rows so MFMA on them is harmless
        Ah[(size_t)row * 256 + tid] = 0;
        Al[(size_t)row * 256 + tid] = 0;
        if (tid == 0) q2[row] = 0.0f;
        return;
    }
    float v = x[(size_t)row * 256 + tid];
    float ss = v * v;
    #pragma unroll
    for (int s = 1; s < 64; s <<= 1) ss += __shfl_xor(ss, s);
    __shared__ float partial[4];
    __shared__ float partial2[4];
    if ((tid & 63) == 0) partial[tid >> 6] = ss;
    __syncthreads();
    float tot = partial[0] + partial[1] + partial[2] + partial[3];
    float inv = 1.0f / sqrtf(tot);
    float val = v * inv - center[tid];
    unsigned short hb = bf16_rn(val);
    float hf = __uint_as_float((unsigned int)hb << 16);
    unsigned short lb = bf16_rn(val - hf);
    Ah[(size_t)row * 256 + tid] = hb;
    Al[(size_t)row * 256 + tid] = lb;
    float ss2 = val * val;
    #pragma unroll
    for (int s = 1; s < 64; s <<= 1) ss2 += __shfl_xor(ss2, s);
    if ((tid & 63) == 0) partial2[tid >> 6] = ss2;
    __syncthreads();
    if (tid == 0) q2[row] = partial2[0] + partial2[1] + partial2[2] + partial2[3];
}

// One wave per train row: bf16 hi/lo split + ||X_t||^2. Pads zeroed, xn2=huge.
__global__ void conv_train(const float* __restrict__ X,
                           unsigned short* __restrict__ Bh, unsigned short* __restrict__ Bl,
                           float* __restrict__ xn2, int nb_train, int Np) {
    int row = blockIdx.x * 4 + (threadIdx.x >> 6);
    int lane = threadIdx.x & 63;
    if (row >= Np) return;
    if (row >= nb_train) {
        ushort4 z = make_ushort4(0, 0, 0, 0);
        *(ushort4*)(Bh + (size_t)row * 256 + lane * 4) = z;
        *(ushort4*)(Bl + (size_t)row * 256 + lane * 4) = z;
        if (lane == 0) xn2[row] = 3.0e38f;
        return;
    }
    float4 v = ((const float4*)(X + (size_t)row * 256))[lane];
    ushort4 h, l;
    h.x = bf16_rn(v.x); l.x = bf16_rn(v.x - __uint_as_float((unsigned)h.x << 16));
    h.y = bf16_rn(v.y); l.y = bf16_rn(v.y - __uint_as_float((unsigned)h.y << 16));
    h.z = bf16_rn(v.z); l.z = bf16_rn(v.z - __uint_as_float((unsigned)h.z << 16));
    h.w = bf16_rn(v.w); l.w = bf16_rn(v.w - __uint_as_float((unsigned)h.w << 16));
    *(ushort4*)(Bh + (size_t)row * 256 + lane * 4) = h;
    *(ushort4*)(Bl + (size_t)row * 256 + lane * 4) = l;
    float ss = v.x * v.x + v.y * v.y + v.z * v.z + v.w * v.w;
    #pragma unroll
    for (int s = 1; s < 64; s <<= 1) ss += __shfl_xor(ss, s);
    if (lane == 0) xn2[row] = ss;
}

// 128x128 tile, 4 waves each computing a 64x64 quadrant (4x4 frags of 16x16x32).
// K-loop: 12 steps of BK=64 over effective K=768 (phase 0: Ah.Bh, 1: Ah.Bl, 2: Al.Bh).
// Staging: per wave 8x global_load_lds(16B/lane) = 8KB; chunk-XOR swizzle via source
// address so compute ds_read_b128 is 2-way bank aliased (free).
__global__ __launch_bounds__(256, 3) void mfma_tile(
    const unsigned short* __restrict__ Adata,  // [Ah | Al], each Mp*256
    const unsigned short* __restrict__ Bdata,  // [Bh | Bl], each Np*256
    const float* __restrict__ q2, const float* __restrict__ xn2,
    unsigned long long* __restrict__ gkey,
    int Mp, int Np, int nb_train, int B)
{
    __shared__ unsigned short As[128 * 64];   // [row][chunk^ (row&7)] 16B chunks
    __shared__ unsigned short Bs[128 * 64];
    __shared__ unsigned long long skey[128];

    const int tid  = threadIdx.x;
    const int wave = tid >> 6;
    const int lane = tid & 63;
    const int mtile = blockIdx.y * 128;
    const int ntile = blockIdx.x * 128;

    if (tid < 128) skey[tid] = ~0ULL;

    // ---- staging role: waves 0,1 stage A rows [0:64),[64:128); waves 2,3 same for B
    const int isB   = wave >> 1;
    const int Rwave = (wave & 1) * 64;
    const int lrow8  = lane >> 3;   // row within 8-row segment
    const int lchunk = lane & 7;    // LDS chunk slot
    const size_t APROD = (size_t)Mp * 256;
    const size_t BPROD = (size_t)Np * 256;
    // source chunk = lds chunk ^ (row&7); row&7 == lrow8 (segment bases are x8)
    const unsigned short* sbase = isB
        ? (Bdata + (size_t)(ntile + Rwave + lrow8) * 256 + (size_t)((lchunk ^ lrow8) * 8))
        : (Adata + (size_t)(mtile + Rwave + lrow8) * 256 + (size_t)((lchunk ^ lrow8) * 8));
    unsigned short* lwave = (isB ? Bs : As) + Rwave * 64;

    // ---- compute role: quadrant
    const int mq = (wave >> 1) * 64;
    const int nq = (wave & 1) * 64;
    const int lrow = lane & 15;
    const int kseg = lane >> 4;
    const int sw = lrow & 7;

    float4v acc[4][4];
    #pragma unroll
    for (int i = 0; i < 4; ++i)
        #pragma unroll
        for (int j = 0; j < 4; ++j)
            acc[i][j] = (float4v){0.f, 0.f, 0.f, 0.f};

    for (int s = 0; s < 12; ++s) {
        const int phase = s >> 2;
        const int sk = (s & 3) * 64;
        size_t srcOff = (size_t)sk;
        if (!isB) { if (phase == 2) srcOff += APROD; }   // Al in phase 2
        else      { if (phase == 1) srcOff += BPROD; }   // Bl in phase 1
        const unsigned short* g = sbase + srcOff;
        __syncthreads();   // previous step's compute done before overwrite
        #pragma unroll
        for (int q = 0; q < 8; ++q)
            gload_lds16(g + q * 2048, lwave + q * 512);
        __syncthreads();   // staging complete (vmcnt drain + barrier)
        #pragma unroll
        for (int t = 0; t < 2; ++t) {
            const int wch = ((t * 4 + kseg) ^ sw) * 8;
            short8 a[4], b[4];
            #pragma unroll
            for (int i = 0; i < 4; ++i)
                a[i] = *(const short8*)&As[(mq + i * 16 + lrow) * 64 + wch];
            #pragma unroll
            for (int j = 0; j < 4; ++j)
                b[j] = *(const short8*)&Bs[(nq + j * 16 + lrow) * 64 + wch];
            #pragma unroll
            for (int i = 0; i < 4; ++i)
                #pragma unroll
                for (int j = 0; j < 4; ++j)
                    acc[i][j] = __builtin_amdgcn_mfma_f32_16x16x32_bf16(
                        a[i], b[j], acc[i][j], 0, 0, 0);
        }
    }

    // ---- epilogue: score = q2[m] - 2*dot + xn2[t]; packed argmin ----
    float xnv[4];
    #pragma unroll
    for (int j = 0; j < 4; ++j)
        xnv[j] = xn2[ntile + nq + j * 16 + lrow];   // pads hold 3e38

    #pragma unroll
    for (int i = 0; i < 4; ++i) {
        #pragma unroll
        for (int r = 0; r < 4; ++r) {
            const int lm = mq + i * 16 + kseg * 4 + r;   // block-local query
            const int mi = mtile + lm;
            unsigned long long best = ~0ULL;
            if (mi < B) {
                float q2v = q2[mi];
                #pragma unroll
                for (int j = 0; j < 4; ++j) {
                    int t_ = ntile + nq + j * 16 + lrow;
                    float sc = fmaxf(q2v - 2.0f * acc[i][j][r] + xnv[j], 0.0f);
                    unsigned long long key =
                        ((unsigned long long)__float_as_uint(sc) << 32) | (unsigned int)t_;
                    best = (key < best) ? key : best;
                }
            }
            #pragma unroll
            for (int sft = 1; sft < 16; sft <<= 1) {
                unsigned long long o = __shfl_xor(best, sft);
                best = (o < best) ? o : best;
            }
            if (lrow == 0 && mi < B) atomicMin(&skey[lm], best);
        }
    }
    __syncthreads();
    if (tid < 128) {
        int mi = mtile + tid;
        if (mi < B && skey[tid] != ~0ULL) atomicMin(gkey + mi, skey[tid]);
    }
}

// One wave per query: 75 gathers across lanes, ballot bincount, bisect p-values.
__global__ void classify(const unsigned long long* __restrict__ gkey,
                         const int* __restrict__ labels,
                         const int* __restrict__ nbr,
                         const int* __restrict__ cali,
                         float* __restrict__ out,
                         int knm1, int nb_cali, int B)
{
    int q = blockIdx.x * 4 + (threadIdx.x >> 6);
    int lane = threadIdx.x & 63;
    if (q >= B) return;
    int closest = (int)(gkey[q] & 0xFFFFFFFFULL);
    int K = knm1 + 1;   // 75
    int lbl0 = -1, lbl1 = -1;
    if (lane < K) {
        int idx = (lane == 0) ? closest : nbr[(size_t)closest * knm1 + (lane - 1)];
        lbl0 = labels[idx];
    }
    int j2 = lane + 64;
    if (j2 < K) {
        int idx = nbr[(size_t)closest * knm1 + (j2 - 1)];
        lbl1 = labels[idx];
    }
    int bestc = 0, bestp = -1;
    #pragma unroll
    for (int c = 0; c < 10; ++c) {
        int cnt = __popcll(__ballot(lbl0 == c)) + __popcll(__ballot(lbl1 == c));
        int v = K - cnt;
        int lo = 0, hi = nb_cali;
        while (lo < hi) {                 // bisect_left
            int mid = (lo + hi) >> 1;
            if (cali[mid] < v) lo = mid + 1; else hi = mid;
        }
        int p = nb_cali - lo;
        if (p > bestp) { bestp = p; bestc = c; }   // strict > == first-occurrence argmax
    }
    float pv = (float)bestp / (float)nb_cali;
    if (lane < 10)
        out[(size_t)q * 10 + lane] = (lane == bestc) ? pv : 0.0f;
}

extern "C" void kernel_launch(void* const* d_in, const int* in_sizes, int n_in,
                              void* d_out, int out_size, void* d_ws, size_t ws_size,
                              hipStream_t stream) {
    const float* x      = (const float*)d_in[0];
    const float* X      = (const float*)d_in[1];
    const float* center = (const float*)d_in[2];
    const int* labels   = (const int*)d_in[3];
    const int* nbr      = (const int*)d_in[4];
    const int* cali     = (const int*)d_in[5];
    float* out = (float*)d_out;

    const int d        = in_sizes[2];              // 256
    const int B        = in_sizes[0] / d;          // 1024
    const int nb_train = in_sizes[3];              // 100000
    const int knm1     = in_sizes[4] / nb_train;   // 74
    const int nb_cali  = in_sizes[5];              // 1000

    const int Mp = (B + 127) & ~127;               // 1024
    const int Np = (nb_train + 127) & ~127;        // 100096

    char* ws = (char*)d_ws;
    size_t off = 0;
    unsigned long long* gkey = (unsigned long long*)(ws + off); off += (size_t)Mp * 8;
    unsigned short* Adata = (unsigned short*)(ws + off); off += (size_t)Mp * 256 * 2 * 2;
    float* q2 = (float*)(ws + off); off += (size_t)Mp * 4;
    unsigned short* Bdata = (unsigned short*)(ws + off); off += (size_t)Np * 256 * 2 * 2;
    float* xn2 = (float*)(ws + off); off += (size_t)Np * 4;

    unsigned short* Ah = Adata;
    unsigned short* Al = Adata + (size_t)Mp * 256;
    unsigned short* Bh = Bdata;
    unsigned short* Bl = Bdata + (size_t)Np * 256;

    prep_queries<<<Mp, 256, 0, stream>>>(x, center, Ah, Al, q2, gkey, B, Mp);
    conv_train<<<Np / 4, 256, 0, stream>>>(X, Bh, Bl, xn2, nb_train, Np);
    dim3 grid(Np / 128, Mp / 128);
    mfma_tile<<<grid, 256, 0, stream>>>(Adata, Bdata, q2, xn2, gkey,
                                        Mp, Np, nb_train, B);
    classify<<<(B + 3) / 4, 256, 0, stream>>>(gkey, labels, nbr, cali, out,
                                              knm1, nb_cali, B);
}

// Round 4
// 381.910 us; speedup vs baseline: 2.7469x; 1.0374x over previous
//
#include <hip/hip_runtime.h>
#include <stdint.h>

// ---------------------------------------------------------------------------
// DkNN round 4: same 128x128 LDS-staged split-bf16 MFMA GEMM, plus:
//  - XCD-aware block swizzle: each XCD owns a contiguous n-tile slice,
//    m iterates fastest -> B tiles stay in that XCD's private L2.
//  - phase order AhBh, AlBh, AhBl (B side: Bh, Bh-warm, Bl).
//  - __launch_bounds__(256,4): 4 blocks/CU (LDS 33KB allows it).
//  - fused prep kernel (train conv + query prep in one launch).
// ---------------------------------------------------------------------------

typedef __attribute__((ext_vector_type(8))) short short8;   // 8 bf16 = 4 VGPR
typedef __attribute__((ext_vector_type(4))) float float4v;  // MFMA C/D

static __device__ __forceinline__ unsigned short bf16_rn(float f) {
    unsigned int u = __float_as_uint(f);
    unsigned int r = (u + 0x7FFFu + ((u >> 16) & 1u)) >> 16;
    return (unsigned short)r;
}

static __device__ __forceinline__ void gload_lds16(const void* g, void* l) {
    __builtin_amdgcn_global_load_lds(
        (const __attribute__((address_space(1))) unsigned int*)g,
        (__attribute__((address_space(3))) unsigned int*)l, 16, 0, 0);
}

// Fused prep: blocks [0, Np/4) convert train rows (4/block); blocks
// [Np/4, Np/4+Mp) prep one query row each (normalize, center, hi/lo, q2, gkey).
__global__ void prep_all(const float* __restrict__ X, const float* __restrict__ x,
                         const float* __restrict__ center,
                         unsigned short* __restrict__ Bh, unsigned short* __restrict__ Bl,
                         float* __restrict__ xn2,
                         unsigned short* __restrict__ Ah, unsigned short* __restrict__ Al,
                         float* __restrict__ q2, unsigned long long* __restrict__ gkey,
                         int nb_train, int Np, int B, int Mp) {
    const int tid = threadIdx.x;
    const int tb = Np >> 2;
    if (blockIdx.x < (unsigned)tb) {
        // ---- train side: 4 rows per block, one wave each ----
        int row = blockIdx.x * 4 + (tid >> 6);
        int lane = tid & 63;
        if (row >= nb_train) {
            ushort4 z = make_ushort4(0, 0, 0, 0);
            *(ushort4*)(Bh + (size_t)row * 256 + lane * 4) = z;
            *(ushort4*)(Bl + (size_t)row * 256 + lane * 4) = z;
            if (lane == 0) xn2[row] = 3.0e38f;
            return;
        }
        float4 v = ((const float4*)(X + (size_t)row * 256))[lane];
        ushort4 h, l;
        h.x = bf16_rn(v.x); l.x = bf16_rn(v.x - __uint_as_float((unsigned)h.x << 16));
        h.y = bf16_rn(v.y); l.y = bf16_rn(v.y - __uint_as_float((unsigned)h.y << 16));
        h.z = bf16_rn(v.z); l.z = bf16_rn(v.z - __uint_as_float((unsigned)h.z << 16));
        h.w = bf16_rn(v.w); l.w = bf16_rn(v.w - __uint_as_float((unsigned)h.w << 16));
        *(ushort4*)(Bh + (size_t)row * 256 + lane * 4) = h;
        *(ushort4*)(Bl + (size_t)row * 256 + lane * 4) = l;
        float ss = v.x * v.x + v.y * v.y + v.z * v.z + v.w * v.w;
        #pragma unroll
        for (int s = 1; s < 64; s <<= 1) ss += __shfl_xor(ss, s);
        if (lane == 0) xn2[row] = ss;
        return;
    }
    // ---- query side: one row per block, 256 threads (d=256) ----
    int row = blockIdx.x - tb;
    if (row >= Mp) return;
    if (tid == 0) gkey[row] = ~0ULL;
    if (row >= B) {
        Ah[(size_t)row * 256 + tid] = 0;
        Al[(size_t)row * 256 + tid] = 0;
        if (tid == 0) q2[row] = 0.0f;
        return;
    }
    float v = x[(size_t)row * 256 + tid];
    float ss = v * v;
    #pragma unroll
    for (int s = 1; s < 64; s <<= 1) ss += __shfl_xor(ss, s);
    __shared__ float partial[4];
    __shared__ float partial2[4];
    if ((tid & 63) == 0) partial[tid >> 6] = ss;
    __syncthreads();
    float tot = partial[0] + partial[1] + partial[2] + partial[3];
    float inv = 1.0f / sqrtf(tot);
    float val = v * inv - center[tid];
    unsigned short hb = bf16_rn(val);
    float hf = __uint_as_float((unsigned int)hb << 16);
    unsigned short lb = bf16_rn(val - hf);
    Ah[(size_t)row * 256 + tid] = hb;
    Al[(size_t)row * 256 + tid] = lb;
    float ss2 = val * val;
    #pragma unroll
    for (int s = 1; s < 64; s <<= 1) ss2 += __shfl_xor(ss2, s);
    if ((tid & 63) == 0) partial2[tid >> 6] = ss2;
    __syncthreads();
    if (tid == 0) q2[row] = partial2[0] + partial2[1] + partial2[2] + partial2[3];
}

// 128x128 tile, 4 waves each computing a 64x64 quadrant (4x4 frags of 16x16x32).
// K-loop: 12 steps of BK=64, phases 0: Ah.Bh, 1: Al.Bh, 2: Ah.Bl.
// 1D grid, XCD-swizzled: xcd = bid&7 owns n-tile slice [xcd*nper, ...); within
// the slice m iterates fastest so same-n blocks run back-to-back on one XCD.
__global__ __launch_bounds__(256, 4) void mfma_tile(
    const unsigned short* __restrict__ Adata,  // [Ah | Al], each Mp*256
    const unsigned short* __restrict__ Bdata,  // [Bh | Bl], each Np*256
    const float* __restrict__ q2, const float* __restrict__ xn2,
    unsigned long long* __restrict__ gkey,
    int Mp, int Np, int nb_train, int B,
    int ntiles, int nper, int mtiles)
{
    __shared__ unsigned short As[128 * 64];   // [row][chunk ^ (row&7)] 16B chunks
    __shared__ unsigned short Bs[128 * 64];
    __shared__ unsigned long long skey[128];

    const int bid = blockIdx.x;
    const int xcd = bid & 7;
    const int s_  = bid >> 3;
    const int n_t = xcd * nper + (s_ / mtiles);
    const int m_t = s_ - (s_ / mtiles) * mtiles;
    if (n_t >= ntiles) return;
    const int mtile = m_t * 128;
    const int ntile = n_t * 128;

    const int tid  = threadIdx.x;
    const int wave = tid >> 6;
    const int lane = tid & 63;

    if (tid < 128) skey[tid] = ~0ULL;

    // ---- staging role: waves 0,1 stage A rows [0:64),[64:128); waves 2,3 for B
    const int isB   = wave >> 1;
    const int Rwave = (wave & 1) * 64;
    const int lrow8  = lane >> 3;   // row within 8-row segment
    const int lchunk = lane & 7;    // LDS chunk slot
    const size_t APROD = (size_t)Mp * 256;
    const size_t BPROD = (size_t)Np * 256;
    const unsigned short* sbase = isB
        ? (Bdata + (size_t)(ntile + Rwave + lrow8) * 256 + (size_t)((lchunk ^ lrow8) * 8))
        : (Adata + (size_t)(mtile + Rwave + lrow8) * 256 + (size_t)((lchunk ^ lrow8) * 8));
    unsigned short* lwave = (isB ? Bs : As) + Rwave * 64;

    // ---- compute role: quadrant
    const int mq = (wave >> 1) * 64;
    const int nq = (wave & 1) * 64;
    const int lrow = lane & 15;
    const int kseg = lane >> 4;
    const int sw = lrow & 7;

    float4v acc[4][4];
    #pragma unroll
    for (int i = 0; i < 4; ++i)
        #pragma unroll
        for (int j = 0; j < 4; ++j)
            acc[i][j] = (float4v){0.f, 0.f, 0.f, 0.f};

    for (int s = 0; s < 12; ++s) {
        const int phase = s >> 2;
        const int sk = (s & 3) * 64;
        size_t srcOff = (size_t)sk;
        if (!isB) { if (phase == 1) srcOff += APROD; }   // Al in phase 1
        else      { if (phase == 2) srcOff += BPROD; }   // Bl in phase 2
        const unsigned short* g = sbase + srcOff;
        __syncthreads();   // previous step's compute done before overwrite
        #pragma unroll
        for (int q = 0; q < 8; ++q)
            gload_lds16(g + q * 2048, lwave + q * 512);
        __syncthreads();   // staging complete (vmcnt drain + barrier)
        #pragma unroll
        for (int t = 0; t < 2; ++t) {
            const int wch = ((t * 4 + kseg) ^ sw) * 8;
            short8 a[4], b[4];
            #pragma unroll
            for (int i = 0; i < 4; ++i)
                a[i] = *(const short8*)&As[(mq + i * 16 + lrow) * 64 + wch];
            #pragma unroll
            for (int j = 0; j < 4; ++j)
                b[j] = *(const short8*)&Bs[(nq + j * 16 + lrow) * 64 + wch];
            #pragma unroll
            for (int i = 0; i < 4; ++i)
                #pragma unroll
                for (int j = 0; j < 4; ++j)
                    acc[i][j] = __builtin_amdgcn_mfma_f32_16x16x32_bf16(
                        a[i], b[j], acc[i][j], 0, 0, 0);
        }
    }

    // ---- epilogue: score = q2[m] - 2*dot + xn2[t]; packed argmin ----
    float xnv[4];
    #pragma unroll
    for (int j = 0; j < 4; ++j)
        xnv[j] = xn2[ntile + nq + j * 16 + lrow];   // pads hold 3e38

    #pragma unroll
    for (int i = 0; i < 4; ++i) {
        #pragma unroll
        for (int r = 0; r < 4; ++r) {
            const int lm = mq + i * 16 + kseg * 4 + r;   // block-local query
            const int mi = mtile + lm;
            unsigned long long best = ~0ULL;
            if (mi < B) {
                float q2v = q2[mi];
                #pragma unroll
                for (int j = 0; j < 4; ++j) {
                    int t_ = ntile + nq + j * 16 + lrow;
                    float sc = fmaxf(q2v - 2.0f * acc[i][j][r] + xnv[j], 0.0f);
                    unsigned long long key =
                        ((unsigned long long)__float_as_uint(sc) << 32) | (unsigned int)t_;
                    best = (key < best) ? key : best;
                }
            }
            #pragma unroll
            for (int sft = 1; sft < 16; sft <<= 1) {
                unsigned long long o = __shfl_xor(best, sft);
                best = (o < best) ? o : best;
            }
            if (lrow == 0 && mi < B) atomicMin(&skey[lm], best);
        }
    }
    __syncthreads();
    if (tid < 128) {
        int mi = mtile + tid;
        if (mi < B && skey[tid] != ~0ULL) atomicMin(gkey + mi, skey[tid]);
    }
}

// One wave per query: 75 gathers across lanes, ballot bincount, bisect p-values.
__global__ void classify(const unsigned long long* __restrict__ gkey,
                         const int* __restrict__ labels,
                         const int* __restrict__ nbr,
                         const int* __restrict__ cali,
                         float* __restrict__ out,
                         int knm1, int nb_cali, int B)
{
    int q = blockIdx.x * 4 + (threadIdx.x >> 6);
    int lane = threadIdx.x & 63;
    if (q >= B) return;
    int closest = (int)(gkey[q] & 0xFFFFFFFFULL);
    int K = knm1 + 1;   // 75
    int lbl0 = -1, lbl1 = -1;
    if (lane < K) {
        int idx = (lane == 0) ? closest : nbr[(size_t)closest * knm1 + (lane - 1)];
        lbl0 = labels[idx];
    }
    int j2 = lane + 64;
    if (j2 < K) {
        int idx = nbr[(size_t)closest * knm1 + (j2 - 1)];
        lbl1 = labels[idx];
    }
    int bestc = 0, bestp = -1;
    #pragma unroll
    for (int c = 0; c < 10; ++c) {
        int cnt = __popcll(__ballot(lbl0 == c)) + __popcll(__ballot(lbl1 == c));
        int v = K - cnt;
        int lo = 0, hi = nb_cali;
        while (lo < hi) {                 // bisect_left
            int mid = (lo + hi) >> 1;
            if (cali[mid] < v) lo = mid + 1; else hi = mid;
        }
        int p = nb_cali - lo;
        if (p > bestp) { bestp = p; bestc = c; }   // strict > == first-occurrence argmax
    }
    float pv = (float)bestp / (float)nb_cali;
    if (lane < 10)
        out[(size_t)q * 10 + lane] = (lane == bestc) ? pv : 0.0f;
}

extern "C" void kernel_launch(void* const* d_in, const int* in_sizes, int n_in,
                              void* d_out, int out_size, void* d_ws, size_t ws_size,
                              hipStream_t stream) {
    const float* x      = (const float*)d_in[0];
    const float* X      = (const float*)d_in[1];
    const float* center = (const float*)d_in[2];
    const int* labels   = (const int*)d_in[3];
    const int* nbr      = (const int*)d_in[4];
    const int* cali     = (const int*)d_in[5];
    float* out = (float*)d_out;

    const int d        = in_sizes[2];              // 256
    const int B        = in_sizes[0] / d;          // 1024
    const int nb_train = in_sizes[3];              // 100000
    const int knm1     = in_sizes[4] / nb_train;   // 74
    const int nb_cali  = in_sizes[5];              // 1000

    const int Mp = (B + 127) & ~127;               // 1024
    const int Np = (nb_train + 127) & ~127;        // 100096

    char* ws = (char*)d_ws;
    size_t off = 0;
    unsigned long long* gkey = (unsigned long long*)(ws + off); off += (size_t)Mp * 8;
    unsigned short* Adata = (unsigned short*)(ws + off); off += (size_t)Mp * 256 * 2 * 2;
    float* q2 = (float*)(ws + off); off += (size_t)Mp * 4;
    unsigned short* Bdata = (unsigned short*)(ws + off); off += (size_t)Np * 256 * 2 * 2;
    float* xn2 = (float*)(ws + off); off += (size_t)Np * 4;

    unsigned short* Ah = Adata;
    unsigned short* Al = Adata + (size_t)Mp * 256;
    unsigned short* Bh = Bdata;
    unsigned short* Bl = Bdata + (size_t)Np * 256;

    prep_all<<<Np / 4 + Mp, 256, 0, stream>>>(X, x, center, Bh, Bl, xn2,
                                              Ah, Al, q2, gkey,
                                              nb_train, Np, B, Mp);
    const int ntiles = Np / 128;                   // 782
    const int mtiles = Mp / 128;                   // 8
    const int nper   = (ntiles + 7) / 8;           // 98
    mfma_tile<<<8 * nper * mtiles, 256, 0, stream>>>(
        Adata, Bdata, q2, xn2, gkey, Mp, Np, nb_train, B, ntiles, nper, mtiles);
    classify<<<(B + 3) / 4, 256, 0, stream>>>(gkey, labels, nbr, cali, out,
                                              knm1, nb_cali, B);
}